// Round 7
// baseline (446.176 us; speedup 1.0000x reference)
//
#include <hip/hip_runtime.h>
#include <math.h>

#define BB_ 32   // batch
#define PP_ 24   // sentences
#define SS_ 48   // tokens
#define HH_ 512  // hidden
#define FF_ 64   // feature
#define DD_ 576  // H+F
#define G4_ 2048 // 4H

typedef __attribute__((ext_vector_type(8))) short short8;
typedef __attribute__((ext_vector_type(4))) float f32x4;

__device__ __forceinline__ float sigf(float x) { return 1.f / (1.f + expf(-x)); }

__device__ __forceinline__ unsigned short f2bf(float f) {
    unsigned int u = __float_as_uint(f);
    u += 0x7FFFu + ((u >> 16) & 1u);     // RNE
    return (unsigned short)(u >> 16);
}

// ---------------------------------------------------------------------------
// LAUNCH 1: fused [attn | weight prep | zeroing]. grid 2465 x 256.
//  blk [0,768):     attention+pooling; also writes bf16 copy of seq row
//  blk [768,1280):  Whh_f -> bf16 B-fragment order (64-block fwd tiling)
//  blk [1280,2432): Wih_f -> bf16 row-major
//  blk [2432,2464): zero AfA (h0 fragments)
//  blk 2464:        zero lstm barrier flags
// ---------------------------------------------------------------------------
__global__ void __launch_bounds__(256) prep_attn_kernel(
        const int* __restrict__ x, const unsigned int* __restrict__ maskw,
        const float* __restrict__ x_feature, const float* __restrict__ emb,
        const float* __restrict__ w_attn, const float* __restrict__ b_attn,
        const float* __restrict__ Whh, unsigned short* __restrict__ Bf,
        const float* __restrict__ Wih, unsigned short* __restrict__ Wbf,
        float* __restrict__ AfA, int* __restrict__ flags,
        float* __restrict__ seq, unsigned short* __restrict__ seqb)
{
    int blk = blockIdx.x, tid = threadIdx.x;
    if (blk < 768) {
        __shared__ float sc_s[SS_], alpha_s[SS_];
        __shared__ int vtok[SS_], vpos[SS_];
        __shared__ int nv_s, s_u8, s_f32;
        __shared__ int idx_s[SS_];
        __shared__ unsigned char msk_s[SS_];
        if (tid == 0) { s_u8 = 0; s_f32 = 0; }
        __syncthreads();
        int u8 = 0, f32 = 0;
        for (int i = tid; i < 9216; i += 256) {     // mask dtype detect (L2-hot)
            unsigned int w = maskw[i];
            if (w == 0x3F800000u) f32 = 1;
            else if (w > 1u) u8 = 1;
        }
        if (u8) s_u8 = 1;
        if (f32) s_f32 = 1;
        __syncthreads();
        int mode = s_f32 ? 2 : (s_u8 ? 1 : 0);
        int bp = blk, b = bp / PP_, p = bp % PP_;
        if (tid < SS_) {
            size_t i = (size_t)bp * SS_ + tid;
            idx_s[tid] = x[i];
            unsigned char mv;
            if (mode == 1)      mv = ((const unsigned char*)maskw)[i];
            else if (mode == 2) mv = (((const float*)maskw)[i] != 0.f);
            else                mv = (((const int*)maskw)[i] != 0);
            msk_s[tid] = mv;
        }
        __syncthreads();
        if (tid == 0) {                              // compact valid tokens
            int nv = 0;
            for (int s = 0; s < SS_; ++s)
                if (!msk_s[s]) { vtok[nv] = idx_s[s]; vpos[nv] = s; ++nv; }
            nv_s = nv;
        }
        __syncthreads();
        int nv = nv_s;
        int wave = tid >> 6, lane = tid & 63;
        float4 wa0 = ((const float4*)w_attn)[lane];        // regs, no LDS bank hits
        float4 wa1 = ((const float4*)w_attn)[64 + lane];
        for (int j = wave; j < nv; j += 4) {
            const float4* er4 = (const float4*)(emb + (size_t)vtok[j] * HH_);
            float4 v0 = er4[lane], v1 = er4[64 + lane];    // coalesced full row
            float acc = v0.x * wa0.x + v0.y * wa0.y + v0.z * wa0.z + v0.w * wa0.w
                      + v1.x * wa1.x + v1.y * wa1.y + v1.z * wa1.z + v1.w * wa1.w;
            #pragma unroll
            for (int off = 32; off > 0; off >>= 1) acc += __shfl_down(acc, off, 64);
            if (lane == 0) sc_s[j] = acc + b_attn[0];
        }
        __syncthreads();
        if (tid == 0) {                              // softmax over valid subset
            float m = -3.4e38f;
            for (int j = 0; j < nv; ++j) if (sc_s[j] > m) m = sc_s[j];
            float sum = 0.f;
            for (int j = 0; j < nv; ++j) { float a = expf(sc_s[j] - m); alpha_s[j] = a; sum += a; }
            float inv = (nv > 0) ? (1.f / sum) : 0.f;
            for (int j = 0; j < nv; ++j) alpha_s[j] *= inv;
        }
        __syncthreads();
        float acc0 = 0.f, acc1 = 0.f;
        for (int j = 0; j < nv; ++j) {               // branch-free, pipelines
            float a = alpha_s[j];
            const float* er = emb + (size_t)vtok[j] * HH_;
            acc0 += a * er[tid];
            acc1 += a * er[tid + 256];
        }
        float* orow = seq + ((size_t)p * BB_ + b) * DD_;
        unsigned short* ob = seqb + ((size_t)p * BB_ + b) * DD_;
        orow[tid] = acc0;
        orow[tid + 256] = acc1;
        ob[tid] = f2bf(acc0);
        ob[tid + 256] = f2bf(acc1);
        if (tid < FF_) {
            float accF = 0.f;
            for (int j = 0; j < nv; ++j)
                accF += x_feature[((size_t)bp * SS_ + vpos[j]) * FF_ + tid];
            orow[HH_ + tid] = accF;
            ob[HH_ + tid] = f2bf(accF);
        }
    } else if (blk < 1280) {
        int idx = (blk - 768) * 256 + tid;          // Whh -> B-fragment order (64-blk)
        int lane = idx & 63;
        int ks = (idx >> 6) & 15;
        int ti = (idx >> 10) & 1;
        int nb = idx >> 11;
        int c = lane & 15, q = lane >> 4;
        int nrow = (ti * 2 + (c >> 3)) * HH_ + nb * 8 + (c & 7);
        int k0 = ks * 32 + q * 8;
        const float* src = Whh + (size_t)nrow * HH_ + k0;
        unsigned int w0 = (unsigned int)f2bf(src[0]) | ((unsigned int)f2bf(src[1]) << 16);
        unsigned int w1 = (unsigned int)f2bf(src[2]) | ((unsigned int)f2bf(src[3]) << 16);
        unsigned int w2 = (unsigned int)f2bf(src[4]) | ((unsigned int)f2bf(src[5]) << 16);
        unsigned int w3 = (unsigned int)f2bf(src[6]) | ((unsigned int)f2bf(src[7]) << 16);
        *(uint4*)(Bf + (size_t)idx * 8) = make_uint4(w0, w1, w2, w3);
    } else if (blk < 2432) {
        int i = (blk - 1280) * 256 + tid;           // Wih -> bf16 (294912 x4)
        float4 v = ((const float4*)Wih)[i];
        ushort4 o;
        o.x = f2bf(v.x); o.y = f2bf(v.y); o.z = f2bf(v.z); o.w = f2bf(v.w);
        ((ushort4*)Wbf)[i] = o;
    } else if (blk < 2464) {
        int idx = (blk - 2432) * 256 + tid;
        if (idx < 8192) AfA[idx] = 0.f;             // h0 fragments = 0
    } else {
        if (tid < 64) flags[tid] = 0;
    }
}

// ---------------------------------------------------------------------------
// LAUNCH 2: input-gate GEMM via MFMA bf16. A is pre-converted bf16 (seqb) --
// no per-iteration f2bf VALU work.
// ---------------------------------------------------------------------------
__global__ void __launch_bounds__(256) in_gates_mfma_kernel(
        const unsigned short* __restrict__ Ab,
        const unsigned short* __restrict__ Wbf,
        const float* __restrict__ bih,
        const float* __restrict__ bhh,
        float* __restrict__ Cout)
{
    int tid = threadIdx.x, lane = tid & 63, w = tid >> 6;
    int m0 = blockIdx.y * 16;
    int nb = blockIdx.x * 128 + w * 32;
    int c = lane & 15, q = lane >> 4;
    const unsigned short* Ap  = Ab  + (size_t)(m0 + c) * DD_ + q * 8;
    const unsigned short* Bp0 = Wbf + (size_t)(nb + c) * DD_ + q * 8;
    const unsigned short* Bp1 = Bp0 + 16 * DD_;
    f32x4 acc0 = {0.f, 0.f, 0.f, 0.f}, acc1 = {0.f, 0.f, 0.f, 0.f};
    for (int k = 0; k < DD_; k += 32) {
        short8 a  = *(const short8*)(Ap  + k);
        short8 b0 = *(const short8*)(Bp0 + k);
        short8 b1 = *(const short8*)(Bp1 + k);
        acc0 = __builtin_amdgcn_mfma_f32_16x16x32_bf16(a, b0, acc0, 0, 0, 0);
        acc1 = __builtin_amdgcn_mfma_f32_16x16x32_bf16(a, b1, acc1, 0, 0, 0);
    }
    #pragma unroll
    for (int r = 0; r < 4; ++r) {
        int m = m0 + q * 4 + r;
        int n0 = nb + c, n1 = nb + 16 + c;
        Cout[(size_t)m * G4_ + n0] = acc0[r] + bih[n0] + bhh[n0];
        Cout[(size_t)m * G4_ + n1] = acc1[r] + bih[n1] + bhh[n1];
    }
}

// ---------------------------------------------------------------------------
// LAUNCH 3: fused [persistent fwd LSTM | backward one-step]. grid 128 x 256.
//  blk [0,64):   persistent LSTM -- R0 structure with a shortened producer
//                tail: wave-local vmcnt drain (only wave0 stores; validated
//                R2/R3) + per-wave flag polling (validated R3/R4). Barriers
//                per step: 2 (gl-sync, hstage-sync). Cross-wave ordering
//                audit: all gl/hstage reads at step t complete before
//                hstage-sync(t); any wave's gl/hstage writes at t+1 happen
//                after gl-sync(t+1), which wave0 reaches only after its
//                pack-reads/drain/flag/poll/a-loads/MFMA at t.
//  blk [64,128): backward-LSTM collapsed single step.
// All 128 blocks co-resident (<=2 blocks/CU at 76 KB LDS) -> no deadlock.
// ---------------------------------------------------------------------------
__global__ void __launch_bounds__(256) lstm_bwd_kernel(
        unsigned short* __restrict__ AfA, unsigned short* __restrict__ AfB,
        float* __restrict__ hbuf, const float* __restrict__ Ain,
        const unsigned short* __restrict__ Bfrag, int* __restrict__ flags,
        const float* __restrict__ seq, const int* __restrict__ lens,
        const float* __restrict__ Wih_b, const float* __restrict__ bih_b,
        const float* __restrict__ bhh_b, float* __restrict__ hbw)
{
    __shared__ float smem[19040];   // union: lstm {gl 1056f + hstage} | bwd {xsT 19008f + pl}
    int tid = threadIdx.x;
    if (blockIdx.x < 64) {
        float* gl = smem;
        unsigned short* hstage = (unsigned short*)(smem + 1056);
        int lane = tid & 63, wv = tid >> 6;
        int mt = wv & 1, ti = wv >> 1;
        int nb = blockIdx.x;
        const short8* Bp = (const short8*)Bfrag + (((size_t)nb * 2 + ti) * 16) * 64 + lane;
        short8 bfr[16];
        #pragma unroll
        for (int ks = 0; ks < 16; ++ks) bfr[ks] = Bp[ks * 64];
        int c = lane & 15, q = lane >> 4;
        int g = ti * 2 + (c >> 3), ul = c & 7;
        int b2 = tid >> 3, u2 = tid & 7;
        int ug = nb * 8 + u2;
        float creg = 0.f;
        for (int t = 0; t < PP_; ++t) {
            const unsigned short* Af = (t & 1) ? AfB : AfA;
            unsigned short* An       = (t & 1) ? AfA : AfB;
            const float* Ain_t = Ain + (size_t)t * BB_ * G4_;
            float ainv[4];
            #pragma unroll
            for (int r = 0; r < 4; ++r)
                ainv[r] = Ain_t[(size_t)(mt * 16 + q * 4 + r) * G4_ + g * HH_ + nb * 8 + ul];
            const unsigned long long* Ap64 =
                (const unsigned long long*)Af + ((size_t)(mt * 16) * 64 + lane) * 2;
            short8 a[16];
            #pragma unroll
            for (int ks = 0; ks < 16; ++ks) {
                unsigned long long lo = __hip_atomic_load(Ap64 + (size_t)ks * 128,
                        __ATOMIC_RELAXED, __HIP_MEMORY_SCOPE_AGENT);
                unsigned long long hi = __hip_atomic_load(Ap64 + (size_t)ks * 128 + 1,
                        __ATOMIC_RELAXED, __HIP_MEMORY_SCOPE_AGENT);
                union { unsigned long long u[2]; short8 s; } cv;
                cv.u[0] = lo; cv.u[1] = hi;
                a[ks] = cv.s;
            }
            // two independent accumulator chains -> half the serial MFMA latency
            f32x4 acA = {0.f, 0.f, 0.f, 0.f}, acB = {0.f, 0.f, 0.f, 0.f};
            #pragma unroll
            for (int ks = 0; ks < 16; ks += 2) {
                acA = __builtin_amdgcn_mfma_f32_16x16x32_bf16(a[ks],     bfr[ks],     acA, 0, 0, 0);
                acB = __builtin_amdgcn_mfma_f32_16x16x32_bf16(a[ks + 1], bfr[ks + 1], acB, 0, 0, 0);
            }
            #pragma unroll
            for (int r = 0; r < 4; ++r) {
                float v = acA[r] + acB[r] + ainv[r];
                v = (g == 2) ? tanhf(v) : sigf(v);
                gl[(g * 8 + ul) * 33 + (mt * 16 + q * 4 + r)] = v;
            }
            __syncthreads();                         // gl-sync
            float iv = gl[(0  + u2) * 33 + b2];
            float fv = gl[(8  + u2) * 33 + b2];
            float gv = gl[(16 + u2) * 33 + b2];
            float ov = gl[(24 + u2) * 33 + b2];
            creg = fv * creg + iv * gv;
            float h = ov * tanhf(creg);
            if (t == PP_ - 1) {
                hbuf[(size_t)b2 * HH_ + ug] = h;
            } else {
                hstage[tid] = f2bf(h);
                __syncthreads();                     // hstage-sync
                if (tid < 64) {
                    int b2s = tid >> 1, hf2 = tid & 1;
                    const unsigned short* hp = &hstage[b2s * 8 + hf2 * 4];
                    unsigned long long v = (unsigned long long)hp[0]
                                         | ((unsigned long long)hp[1] << 16)
                                         | ((unsigned long long)hp[2] << 32)
                                         | ((unsigned long long)hp[3] << 48);
                    size_t ub = ((((size_t)(b2s >> 4)) * 16 + (nb >> 2)) * 64
                                 + ((b2s & 15) + 16 * (nb & 3))) * 8 + hf2 * 4;
                    __hip_atomic_store((unsigned long long*)(An + ub), v,
                                       __ATOMIC_RELAXED, __HIP_MEMORY_SCOPE_AGENT);
                    // wave-local drain: only wave0 has outstanding stores
                    asm volatile("s_waitcnt vmcnt(0)" ::: "memory");
                    if (tid == 0)
                        __hip_atomic_store(&flags[nb], t + 1,
                                           __ATOMIC_RELAXED, __HIP_MEMORY_SCOPE_AGENT);
                }
                // per-wave poll: each wave proceeds to its a-loads the
                // moment IT sees all 64 producer flags -- no re-convergence.
                {
                    int target = t + 1;
                    while (true) {
                        int v = __hip_atomic_load(&flags[lane],
                                __ATOMIC_RELAXED, __HIP_MEMORY_SCOPE_AGENT);
                        if (__all(v >= target)) break;
                        __builtin_amdgcn_s_sleep(1);
                    }
                }
            }
        }
    } else {
        float* xsT = smem;
        int* pl = (int*)(smem + 19008);
        int blk2 = blockIdx.x - 64;
        if (tid < BB_) pl[tid] = lens[tid] - 1;
        __syncthreads();
        for (int idx = tid; idx < BB_ * DD_; idx += 256) {
            int b2 = idx / DD_;
            int k = idx - b2 * DD_;
            xsT[k * 33 + b2] = seq[((size_t)pl[b2] * BB_ + b2) * DD_ + k];
        }
        __syncthreads();
        int b = tid & 31, ul = tid >> 5;
        int u = blk2 * 8 + ul;
        const float* wi = Wih_b + (size_t)u * DD_;
        const float* wg = Wih_b + (size_t)(2 * HH_ + u) * DD_;
        const float* wo = Wih_b + (size_t)(3 * HH_ + u) * DD_;
        float gi = 0.f, gg = 0.f, go = 0.f;
        #pragma unroll 4
        for (int k = 0; k < DD_; k += 4) {
            float4 w1 = *(const float4*)(wi + k);
            float4 w2 = *(const float4*)(wg + k);
            float4 w3 = *(const float4*)(wo + k);
            float x0 = xsT[(k + 0) * 33 + b];
            float x1 = xsT[(k + 1) * 33 + b];
            float x2 = xsT[(k + 2) * 33 + b];
            float x3 = xsT[(k + 3) * 33 + b];
            gi += w1.x * x0 + w1.y * x1 + w1.z * x2 + w1.w * x3;
            gg += w2.x * x0 + w2.y * x1 + w2.z * x2 + w2.w * x3;
            go += w3.x * x0 + w3.y * x1 + w3.z * x2 + w3.w * x3;
        }
        gi += bih_b[u] + bhh_b[u];
        gg += bih_b[2 * HH_ + u] + bhh_b[2 * HH_ + u];
        go += bih_b[3 * HH_ + u] + bhh_b[3 * HH_ + u];
        float cc = sigf(gi) * tanhf(gg);   // c0 = 0
        hbw[(size_t)b * HH_ + u] = sigf(go) * tanhf(cc);
    }
}

// ---------------------------------------------------------------------------
// LAUNCH 4: fused head, one block x 1024 thr (unchanged).
// ---------------------------------------------------------------------------
__global__ void __launch_bounds__(1024) head_fused_kernel(
        const float* __restrict__ hf, const float* __restrict__ hbwd,
        const int* __restrict__ lens,
        const float* __restrict__ Wfc, const float* __restrict__ bfc,
        const float* __restrict__ gamma, const float* __restrict__ beta,
        float* __restrict__ out)
{
    __shared__ float tileL[32 * 1024];   // 128 KB
    __shared__ float lmask[BB_];
    __shared__ float part[1024];
    __shared__ float ys[16][33];
    __shared__ float cstat[16];
    int tid = threadIdx.x;
    if (tid < BB_) lmask[tid] = (lens[tid] == PP_) ? 1.f : 0.f;
    __syncthreads();
    for (int j = tid; j < 32 * 1024; j += 1024) {
        int bb = j >> 10, col = j & 1023;
        float v = (col < HH_) ? hf[(size_t)bb * HH_ + col]
                              : hbwd[(size_t)bb * HH_ + col - HH_];
        tileL[j] = v * lmask[bb];
    }
    __syncthreads();
    int outi = tid & 511, half = tid >> 9;
    int i = outi >> 4, o = outi & 15;
    const float* wrow = Wfc + (size_t)o * 1024;
    float acc = 0.f;
    for (int q = 0; q < 32; ++q) {
        int j = i * 32 + q;
        #pragma unroll
        for (int bb2 = 0; bb2 < 16; ++bb2) {
            int bb = half * 16 + bb2;
            acc += tileL[bb * 1024 + j] * wrow[q * 32 + bb];
        }
    }
    part[tid] = acc;
    __syncthreads();
    if (tid < 512) ys[o][i] = part[tid] + part[tid + 512] + bfc[o];
    __syncthreads();
    if (tid < 16) {
        float mean = 0.f;
        for (int ii = 0; ii < 32; ++ii) mean += ys[tid][ii];
        mean *= (1.f / 32.f);
        float var = 0.f;
        for (int ii = 0; ii < 32; ++ii) { float d = ys[tid][ii] - mean; var += d * d; }
        var *= (1.f / 32.f);
        float inv = 1.f / sqrtf(var + 1e-5f);
        float gmm = gamma[tid], bt = beta[tid];
        float mx = -3.4e38f;
        for (int ii = 0; ii < 32; ++ii) {
            float v = gmm * (ys[tid][ii] - mean) * inv + bt;
            v = fmaxf(v, 0.f);
            ys[tid][ii] = v;
            mx = fmaxf(mx, v);
        }
        float s = 0.f;
        for (int ii = 0; ii < 32; ++ii) s += expf(ys[tid][ii] - mx);
        cstat[tid] = mx + logf(s);
    }
    __syncthreads();
    if (tid < 512) out[tid] = ys[o][i] - cstat[o];
}

extern "C" void kernel_launch(void* const* d_in, const int* in_sizes, int n_in,
                              void* d_out, int out_size, void* d_ws, size_t ws_size,
                              hipStream_t stream) {
    const int* x            = (const int*)d_in[0];
    const void* xm          = d_in[1];
    const float* x_feature  = (const float*)d_in[2];
    const int* lens         = (const int*)d_in[3];
    const float* emb    = (const float*)d_in[6];
    const float* w_attn = (const float*)d_in[7];
    const float* b_attn = (const float*)d_in[8];
    const float* Wih_f  = (const float*)d_in[9];
    const float* Whh_f  = (const float*)d_in[10];
    const float* bih_f  = (const float*)d_in[11];
    const float* bhh_f  = (const float*)d_in[12];
    const float* Wih_b  = (const float*)d_in[13];
    const float* bih_b  = (const float*)d_in[15];
    const float* bhh_b  = (const float*)d_in[16];
    const float* Wfc    = (const float*)d_in[17];
    const float* bfc    = (const float*)d_in[18];
    const float* gamma  = (const float*)d_in[19];
    const float* beta   = (const float*)d_in[20];

    float* ws    = (float*)d_ws;
    float* seq   = ws;                                    // 442368 f
    float* Ain   = seq + (size_t)PP_ * BB_ * DD_;         // 1572864 f
    float* hb    = Ain + (size_t)PP_ * BB_ * G4_;         // 16384 f
    float* hbuf  = hb + (size_t)BB_ * HH_;                // 16384 f
    float* AfA   = hbuf + (size_t)BB_ * HH_;              // 8192 f (16384 bf16)
    float* AfB   = AfA + 8192;                            // 8192 f
    float* Bfrag = AfB + 8192;                            // 524288 f (1M bf16)
    float* Wbf   = Bfrag + 524288;                        // 589824 f (1.18M bf16)
    int*  flags  = (int*)(Wbf + 589824);                  // 64 i (16 f)
    unsigned short* seqb = (unsigned short*)(Wbf + 589824 + 16);  // 442368 bf16

    float* outp = (float*)d_out;

    prep_attn_kernel<<<dim3(2465), dim3(256), 0, stream>>>(
        x, (const unsigned int*)xm, x_feature, emb, w_attn, b_attn,
        Whh_f, (unsigned short*)Bfrag, Wih_f, (unsigned short*)Wbf,
        AfA, flags, seq, seqb);
    in_gates_mfma_kernel<<<dim3(16, 48), dim3(256), 0, stream>>>(
        seqb, (const unsigned short*)Wbf, bih_f, bhh_f, Ain);
    lstm_bwd_kernel<<<dim3(128), dim3(256), 0, stream>>>(
        (unsigned short*)AfA, (unsigned short*)AfB, hbuf, Ain,
        (const unsigned short*)Bfrag, flags,
        seq, lens, Wih_b, bih_b, bhh_b, hb);
    head_fused_kernel<<<dim3(1), dim3(1024), 0, stream>>>(
        hbuf, hb, lens, Wfc, bfc, gamma, beta, outp);
}

// Round 8
// 408.352 us; speedup vs baseline: 1.0926x; 1.0926x over previous
//
#include <hip/hip_runtime.h>
#include <math.h>

#define BB_ 32   // batch
#define PP_ 24   // sentences
#define SS_ 48   // tokens
#define HH_ 512  // hidden
#define FF_ 64   // feature
#define DD_ 576  // H+F
#define G4_ 2048 // 4H

typedef __attribute__((ext_vector_type(8))) short short8;
typedef __attribute__((ext_vector_type(4))) float f32x4;

__device__ __forceinline__ float sigf(float x) { return 1.f / (1.f + expf(-x)); }

__device__ __forceinline__ unsigned short f2bf(float f) {
    unsigned int u = __float_as_uint(f);
    u += 0x7FFFu + ((u >> 16) & 1u);     // RNE
    return (unsigned short)(u >> 16);
}

// ---------------------------------------------------------------------------
// LAUNCH 1: fused [attn | weight prep | zeroing]. grid 2465 x 256.
//  blk [0,768):     attention+pooling; also writes bf16 copy of seq row
//  blk [768,1280):  Whh_f -> bf16 B-fragment order (64-block fwd tiling)
//  blk [1280,2432): Wih_f -> bf16 row-major
//  blk [2432,2464): zero AfA (h0 fragments)
//  blk 2464:        zero lstm barrier flags (PADDED: one flag per 256B line)
// ---------------------------------------------------------------------------
__global__ void __launch_bounds__(256) prep_attn_kernel(
        const int* __restrict__ x, const unsigned int* __restrict__ maskw,
        const float* __restrict__ x_feature, const float* __restrict__ emb,
        const float* __restrict__ w_attn, const float* __restrict__ b_attn,
        const float* __restrict__ Whh, unsigned short* __restrict__ Bf,
        const float* __restrict__ Wih, unsigned short* __restrict__ Wbf,
        float* __restrict__ AfA, int* __restrict__ flags,
        float* __restrict__ seq, unsigned short* __restrict__ seqb)
{
    int blk = blockIdx.x, tid = threadIdx.x;
    if (blk < 768) {
        __shared__ float sc_s[SS_], alpha_s[SS_];
        __shared__ int vtok[SS_], vpos[SS_];
        __shared__ int nv_s, s_u8, s_f32;
        __shared__ int idx_s[SS_];
        __shared__ unsigned char msk_s[SS_];
        if (tid == 0) { s_u8 = 0; s_f32 = 0; }
        __syncthreads();
        int u8 = 0, f32 = 0;
        for (int i = tid; i < 9216; i += 256) {     // mask dtype detect (L2-hot)
            unsigned int w = maskw[i];
            if (w == 0x3F800000u) f32 = 1;
            else if (w > 1u) u8 = 1;
        }
        if (u8) s_u8 = 1;
        if (f32) s_f32 = 1;
        __syncthreads();
        int mode = s_f32 ? 2 : (s_u8 ? 1 : 0);
        int bp = blk, b = bp / PP_, p = bp % PP_;
        if (tid < SS_) {
            size_t i = (size_t)bp * SS_ + tid;
            idx_s[tid] = x[i];
            unsigned char mv;
            if (mode == 1)      mv = ((const unsigned char*)maskw)[i];
            else if (mode == 2) mv = (((const float*)maskw)[i] != 0.f);
            else                mv = (((const int*)maskw)[i] != 0);
            msk_s[tid] = mv;
        }
        __syncthreads();
        if (tid == 0) {                              // compact valid tokens
            int nv = 0;
            for (int s = 0; s < SS_; ++s)
                if (!msk_s[s]) { vtok[nv] = idx_s[s]; vpos[nv] = s; ++nv; }
            nv_s = nv;
        }
        __syncthreads();
        int nv = nv_s;
        int wave = tid >> 6, lane = tid & 63;
        float4 wa0 = ((const float4*)w_attn)[lane];        // regs, no LDS bank hits
        float4 wa1 = ((const float4*)w_attn)[64 + lane];
        for (int j = wave; j < nv; j += 4) {
            const float4* er4 = (const float4*)(emb + (size_t)vtok[j] * HH_);
            float4 v0 = er4[lane], v1 = er4[64 + lane];    // coalesced full row
            float acc = v0.x * wa0.x + v0.y * wa0.y + v0.z * wa0.z + v0.w * wa0.w
                      + v1.x * wa1.x + v1.y * wa1.y + v1.z * wa1.z + v1.w * wa1.w;
            #pragma unroll
            for (int off = 32; off > 0; off >>= 1) acc += __shfl_down(acc, off, 64);
            if (lane == 0) sc_s[j] = acc + b_attn[0];
        }
        __syncthreads();
        if (tid == 0) {                              // softmax over valid subset
            float m = -3.4e38f;
            for (int j = 0; j < nv; ++j) if (sc_s[j] > m) m = sc_s[j];
            float sum = 0.f;
            for (int j = 0; j < nv; ++j) { float a = expf(sc_s[j] - m); alpha_s[j] = a; sum += a; }
            float inv = (nv > 0) ? (1.f / sum) : 0.f;
            for (int j = 0; j < nv; ++j) alpha_s[j] *= inv;
        }
        __syncthreads();
        float acc0 = 0.f, acc1 = 0.f;
        for (int j = 0; j < nv; ++j) {               // branch-free, pipelines
            float a = alpha_s[j];
            const float* er = emb + (size_t)vtok[j] * HH_;
            acc0 += a * er[tid];
            acc1 += a * er[tid + 256];
        }
        float* orow = seq + ((size_t)p * BB_ + b) * DD_;
        unsigned short* ob = seqb + ((size_t)p * BB_ + b) * DD_;
        orow[tid] = acc0;
        orow[tid + 256] = acc1;
        ob[tid] = f2bf(acc0);
        ob[tid + 256] = f2bf(acc1);
        if (tid < FF_) {
            float accF = 0.f;
            for (int j = 0; j < nv; ++j)
                accF += x_feature[((size_t)bp * SS_ + vpos[j]) * FF_ + tid];
            orow[HH_ + tid] = accF;
            ob[HH_ + tid] = f2bf(accF);
        }
    } else if (blk < 1280) {
        int idx = (blk - 768) * 256 + tid;          // Whh -> B-fragment order (64-blk)
        int lane = idx & 63;
        int ks = (idx >> 6) & 15;
        int ti = (idx >> 10) & 1;
        int nb = idx >> 11;
        int c = lane & 15, q = lane >> 4;
        int nrow = (ti * 2 + (c >> 3)) * HH_ + nb * 8 + (c & 7);
        int k0 = ks * 32 + q * 8;
        const float* src = Whh + (size_t)nrow * HH_ + k0;
        unsigned int w0 = (unsigned int)f2bf(src[0]) | ((unsigned int)f2bf(src[1]) << 16);
        unsigned int w1 = (unsigned int)f2bf(src[2]) | ((unsigned int)f2bf(src[3]) << 16);
        unsigned int w2 = (unsigned int)f2bf(src[4]) | ((unsigned int)f2bf(src[5]) << 16);
        unsigned int w3 = (unsigned int)f2bf(src[6]) | ((unsigned int)f2bf(src[7]) << 16);
        *(uint4*)(Bf + (size_t)idx * 8) = make_uint4(w0, w1, w2, w3);
    } else if (blk < 2432) {
        int i = (blk - 1280) * 256 + tid;           // Wih -> bf16 (294912 x4)
        float4 v = ((const float4*)Wih)[i];
        ushort4 o;
        o.x = f2bf(v.x); o.y = f2bf(v.y); o.z = f2bf(v.z); o.w = f2bf(v.w);
        ((ushort4*)Wbf)[i] = o;
    } else if (blk < 2464) {
        int idx = (blk - 2432) * 256 + tid;
        if (idx < 8192) AfA[idx] = 0.f;             // h0 fragments = 0
    } else {
        if (tid < 64) flags[tid * 64] = 0;          // padded flags: 1 per 256B
    }
}

// ---------------------------------------------------------------------------
// LAUNCH 2: input-gate GEMM via MFMA bf16. A is pre-converted bf16 (seqb) --
// no per-iteration f2bf VALU work.
// ---------------------------------------------------------------------------
__global__ void __launch_bounds__(256) in_gates_mfma_kernel(
        const unsigned short* __restrict__ Ab,
        const unsigned short* __restrict__ Wbf,
        const float* __restrict__ bih,
        const float* __restrict__ bhh,
        float* __restrict__ Cout)
{
    int tid = threadIdx.x, lane = tid & 63, w = tid >> 6;
    int m0 = blockIdx.y * 16;
    int nb = blockIdx.x * 128 + w * 32;
    int c = lane & 15, q = lane >> 4;
    const unsigned short* Ap  = Ab  + (size_t)(m0 + c) * DD_ + q * 8;
    const unsigned short* Bp0 = Wbf + (size_t)(nb + c) * DD_ + q * 8;
    const unsigned short* Bp1 = Bp0 + 16 * DD_;
    f32x4 acc0 = {0.f, 0.f, 0.f, 0.f}, acc1 = {0.f, 0.f, 0.f, 0.f};
    for (int k = 0; k < DD_; k += 32) {
        short8 a  = *(const short8*)(Ap  + k);
        short8 b0 = *(const short8*)(Bp0 + k);
        short8 b1 = *(const short8*)(Bp1 + k);
        acc0 = __builtin_amdgcn_mfma_f32_16x16x32_bf16(a, b0, acc0, 0, 0, 0);
        acc1 = __builtin_amdgcn_mfma_f32_16x16x32_bf16(a, b1, acc1, 0, 0, 0);
    }
    #pragma unroll
    for (int r = 0; r < 4; ++r) {
        int m = m0 + q * 4 + r;
        int n0 = nb + c, n1 = nb + 16 + c;
        Cout[(size_t)m * G4_ + n0] = acc0[r] + bih[n0] + bhh[n0];
        Cout[(size_t)m * G4_ + n1] = acc1[r] + bih[n1] + bhh[n1];
    }
}

// ---------------------------------------------------------------------------
// LAUNCH 3: fused [persistent fwd LSTM | backward one-step]. grid 128 x 256.
//  blk [0,64):   persistent LSTM -- VERBATIM R0/R6 protocol (measured optimum
//                124.5us), with flags PADDED to one per 256B line to spread
//                poll traffic across L3 slices (R3/R7 showed flag traffic is
//                first-order: 4x poll traffic cost +11-18us).
//  blk [64,128): backward-LSTM collapsed single step.
// All 128 blocks co-resident (<=2 blocks/CU at 76 KB LDS) -> no deadlock.
// ---------------------------------------------------------------------------
__global__ void __launch_bounds__(256) lstm_bwd_kernel(
        unsigned short* __restrict__ AfA, unsigned short* __restrict__ AfB,
        float* __restrict__ hbuf, const float* __restrict__ Ain,
        const unsigned short* __restrict__ Bfrag, int* __restrict__ flags,
        const float* __restrict__ seq, const int* __restrict__ lens,
        const float* __restrict__ Wih_b, const float* __restrict__ bih_b,
        const float* __restrict__ bhh_b, float* __restrict__ hbw)
{
    __shared__ float smem[19040];   // union: lstm {gl 1056f + hstage} | bwd {xsT 19008f + pl}
    int tid = threadIdx.x;
    if (blockIdx.x < 64) {
        float* gl = smem;
        unsigned short* hstage = (unsigned short*)(smem + 1056);
        int lane = tid & 63, wv = tid >> 6;
        int mt = wv & 1, ti = wv >> 1;
        int nb = blockIdx.x;
        const short8* Bp = (const short8*)Bfrag + (((size_t)nb * 2 + ti) * 16) * 64 + lane;
        short8 bfr[16];
        #pragma unroll
        for (int ks = 0; ks < 16; ++ks) bfr[ks] = Bp[ks * 64];
        int c = lane & 15, q = lane >> 4;
        int g = ti * 2 + (c >> 3), ul = c & 7;
        int b2 = tid >> 3, u2 = tid & 7;
        int ug = nb * 8 + u2;
        float creg = 0.f;
        for (int t = 0; t < PP_; ++t) {
            const unsigned short* Af = (t & 1) ? AfB : AfA;
            unsigned short* An       = (t & 1) ? AfA : AfB;
            const float* Ain_t = Ain + (size_t)t * BB_ * G4_;
            float ainv[4];
            #pragma unroll
            for (int r = 0; r < 4; ++r)
                ainv[r] = Ain_t[(size_t)(mt * 16 + q * 4 + r) * G4_ + g * HH_ + nb * 8 + ul];
            const unsigned long long* Ap64 =
                (const unsigned long long*)Af + ((size_t)(mt * 16) * 64 + lane) * 2;
            short8 a[16];
            #pragma unroll
            for (int ks = 0; ks < 16; ++ks) {
                unsigned long long lo = __hip_atomic_load(Ap64 + (size_t)ks * 128,
                        __ATOMIC_RELAXED, __HIP_MEMORY_SCOPE_AGENT);
                unsigned long long hi = __hip_atomic_load(Ap64 + (size_t)ks * 128 + 1,
                        __ATOMIC_RELAXED, __HIP_MEMORY_SCOPE_AGENT);
                union { unsigned long long u[2]; short8 s; } cv;
                cv.u[0] = lo; cv.u[1] = hi;
                a[ks] = cv.s;
            }
            // two independent accumulator chains -> half the serial MFMA latency
            f32x4 acA = {0.f, 0.f, 0.f, 0.f}, acB = {0.f, 0.f, 0.f, 0.f};
            #pragma unroll
            for (int ks = 0; ks < 16; ks += 2) {
                acA = __builtin_amdgcn_mfma_f32_16x16x32_bf16(a[ks],     bfr[ks],     acA, 0, 0, 0);
                acB = __builtin_amdgcn_mfma_f32_16x16x32_bf16(a[ks + 1], bfr[ks + 1], acB, 0, 0, 0);
            }
            #pragma unroll
            for (int r = 0; r < 4; ++r) {
                float v = acA[r] + acB[r] + ainv[r];
                v = (g == 2) ? tanhf(v) : sigf(v);
                gl[(g * 8 + ul) * 33 + (mt * 16 + q * 4 + r)] = v;
            }
            __syncthreads();
            float iv = gl[(0  + u2) * 33 + b2];
            float fv = gl[(8  + u2) * 33 + b2];
            float gv = gl[(16 + u2) * 33 + b2];
            float ov = gl[(24 + u2) * 33 + b2];
            creg = fv * creg + iv * gv;
            float h = ov * tanhf(creg);
            if (t == PP_ - 1) {
                hbuf[(size_t)b2 * HH_ + ug] = h;
            } else {
                hstage[tid] = f2bf(h);
                __syncthreads();
                if (tid < 64) {
                    int b2s = tid >> 1, hf2 = tid & 1;
                    const unsigned short* hp = &hstage[b2s * 8 + hf2 * 4];
                    unsigned long long v = (unsigned long long)hp[0]
                                         | ((unsigned long long)hp[1] << 16)
                                         | ((unsigned long long)hp[2] << 32)
                                         | ((unsigned long long)hp[3] << 48);
                    size_t ub = ((((size_t)(b2s >> 4)) * 16 + (nb >> 2)) * 64
                                 + ((b2s & 15) + 16 * (nb & 3))) * 8 + hf2 * 4;
                    __hip_atomic_store((unsigned long long*)(An + ub), v,
                                       __ATOMIC_RELAXED, __HIP_MEMORY_SCOPE_AGENT);
                }
                __syncthreads();   // vmcnt(0): h stores at coherence point
                if (tid == 0)
                    __hip_atomic_store(&flags[nb * 64], t + 1,
                                       __ATOMIC_RELAXED, __HIP_MEMORY_SCOPE_AGENT);
                if (tid < 64) {
                    int target = t + 1;
                    while (true) {
                        int v = __hip_atomic_load(&flags[tid * 64],
                                __ATOMIC_RELAXED, __HIP_MEMORY_SCOPE_AGENT);
                        if (__all(v >= target)) break;
                        __builtin_amdgcn_s_sleep(1);
                    }
                }
                __syncthreads();
            }
        }
    } else {
        float* xsT = smem;
        int* pl = (int*)(smem + 19008);
        int blk2 = blockIdx.x - 64;
        if (tid < BB_) pl[tid] = lens[tid] - 1;
        __syncthreads();
        for (int idx = tid; idx < BB_ * DD_; idx += 256) {
            int b2 = idx / DD_;
            int k = idx - b2 * DD_;
            xsT[k * 33 + b2] = seq[((size_t)pl[b2] * BB_ + b2) * DD_ + k];
        }
        __syncthreads();
        int b = tid & 31, ul = tid >> 5;
        int u = blk2 * 8 + ul;
        const float* wi = Wih_b + (size_t)u * DD_;
        const float* wg = Wih_b + (size_t)(2 * HH_ + u) * DD_;
        const float* wo = Wih_b + (size_t)(3 * HH_ + u) * DD_;
        float gi = 0.f, gg = 0.f, go = 0.f;
        #pragma unroll 4
        for (int k = 0; k < DD_; k += 4) {
            float4 w1 = *(const float4*)(wi + k);
            float4 w2 = *(const float4*)(wg + k);
            float4 w3 = *(const float4*)(wo + k);
            float x0 = xsT[(k + 0) * 33 + b];
            float x1 = xsT[(k + 1) * 33 + b];
            float x2 = xsT[(k + 2) * 33 + b];
            float x3 = xsT[(k + 3) * 33 + b];
            gi += w1.x * x0 + w1.y * x1 + w1.z * x2 + w1.w * x3;
            gg += w2.x * x0 + w2.y * x1 + w2.z * x2 + w2.w * x3;
            go += w3.x * x0 + w3.y * x1 + w3.z * x2 + w3.w * x3;
        }
        gi += bih_b[u] + bhh_b[u];
        gg += bih_b[2 * HH_ + u] + bhh_b[2 * HH_ + u];
        go += bih_b[3 * HH_ + u] + bhh_b[3 * HH_ + u];
        float cc = sigf(gi) * tanhf(gg);   // c0 = 0
        hbw[(size_t)b * HH_ + u] = sigf(go) * tanhf(cc);
    }
}

// ---------------------------------------------------------------------------
// LAUNCH 4: fused head, one block x 1024 thr (unchanged).
// ---------------------------------------------------------------------------
__global__ void __launch_bounds__(1024) head_fused_kernel(
        const float* __restrict__ hf, const float* __restrict__ hbwd,
        const int* __restrict__ lens,
        const float* __restrict__ Wfc, const float* __restrict__ bfc,
        const float* __restrict__ gamma, const float* __restrict__ beta,
        float* __restrict__ out)
{
    __shared__ float tileL[32 * 1024];   // 128 KB
    __shared__ float lmask[BB_];
    __shared__ float part[1024];
    __shared__ float ys[16][33];
    __shared__ float cstat[16];
    int tid = threadIdx.x;
    if (tid < BB_) lmask[tid] = (lens[tid] == PP_) ? 1.f : 0.f;
    __syncthreads();
    for (int j = tid; j < 32 * 1024; j += 1024) {
        int bb = j >> 10, col = j & 1023;
        float v = (col < HH_) ? hf[(size_t)bb * HH_ + col]
                              : hbwd[(size_t)bb * HH_ + col - HH_];
        tileL[j] = v * lmask[bb];
    }
    __syncthreads();
    int outi = tid & 511, half = tid >> 9;
    int i = outi >> 4, o = outi & 15;
    const float* wrow = Wfc + (size_t)o * 1024;
    float acc = 0.f;
    for (int q = 0; q < 32; ++q) {
        int j = i * 32 + q;
        #pragma unroll
        for (int bb2 = 0; bb2 < 16; ++bb2) {
            int bb = half * 16 + bb2;
            acc += tileL[bb * 1024 + j] * wrow[q * 32 + bb];
        }
    }
    part[tid] = acc;
    __syncthreads();
    if (tid < 512) ys[o][i] = part[tid] + part[tid + 512] + bfc[o];
    __syncthreads();
    if (tid < 16) {
        float mean = 0.f;
        for (int ii = 0; ii < 32; ++ii) mean += ys[tid][ii];
        mean *= (1.f / 32.f);
        float var = 0.f;
        for (int ii = 0; ii < 32; ++ii) { float d = ys[tid][ii] - mean; var += d * d; }
        var *= (1.f / 32.f);
        float inv = 1.f / sqrtf(var + 1e-5f);
        float gmm = gamma[tid], bt = beta[tid];
        float mx = -3.4e38f;
        for (int ii = 0; ii < 32; ++ii) {
            float v = gmm * (ys[tid][ii] - mean) * inv + bt;
            v = fmaxf(v, 0.f);
            ys[tid][ii] = v;
            mx = fmaxf(mx, v);
        }
        float s = 0.f;
        for (int ii = 0; ii < 32; ++ii) s += expf(ys[tid][ii] - mx);
        cstat[tid] = mx + logf(s);
    }
    __syncthreads();
    if (tid < 512) out[tid] = ys[o][i] - cstat[o];
}

extern "C" void kernel_launch(void* const* d_in, const int* in_sizes, int n_in,
                              void* d_out, int out_size, void* d_ws, size_t ws_size,
                              hipStream_t stream) {
    const int* x            = (const int*)d_in[0];
    const void* xm          = d_in[1];
    const float* x_feature  = (const float*)d_in[2];
    const int* lens         = (const int*)d_in[3];
    const float* emb    = (const float*)d_in[6];
    const float* w_attn = (const float*)d_in[7];
    const float* b_attn = (const float*)d_in[8];
    const float* Wih_f  = (const float*)d_in[9];
    const float* Whh_f  = (const float*)d_in[10];
    const float* bih_f  = (const float*)d_in[11];
    const float* bhh_f  = (const float*)d_in[12];
    const float* Wih_b  = (const float*)d_in[13];
    const float* bih_b  = (const float*)d_in[15];
    const float* bhh_b  = (const float*)d_in[16];
    const float* Wfc    = (const float*)d_in[17];
    const float* bfc    = (const float*)d_in[18];
    const float* gamma  = (const float*)d_in[19];
    const float* beta   = (const float*)d_in[20];

    float* ws    = (float*)d_ws;
    float* seq   = ws;                                    // 442368 f
    float* Ain   = seq + (size_t)PP_ * BB_ * DD_;         // 1572864 f
    float* hb    = Ain + (size_t)PP_ * BB_ * G4_;         // 16384 f
    float* hbuf  = hb + (size_t)BB_ * HH_;                // 16384 f
    float* AfA   = hbuf + (size_t)BB_ * HH_;              // 8192 f (16384 bf16)
    float* AfB   = AfA + 8192;                            // 8192 f
    float* Bfrag = AfB + 8192;                            // 524288 f (1M bf16)
    float* Wbf   = Bfrag + 524288;                        // 589824 f (1.18M bf16)
    int*  flags  = (int*)(Wbf + 589824);                  // 64 flags x 64-int pad
    unsigned short* seqb = (unsigned short*)(Wbf + 589824 + 4096); // 442368 bf16

    float* outp = (float*)d_out;

    prep_attn_kernel<<<dim3(2465), dim3(256), 0, stream>>>(
        x, (const unsigned int*)xm, x_feature, emb, w_attn, b_attn,
        Whh_f, (unsigned short*)Bfrag, Wih_f, (unsigned short*)Wbf,
        AfA, flags, seq, seqb);
    in_gates_mfma_kernel<<<dim3(16, 48), dim3(256), 0, stream>>>(
        seqb, (const unsigned short*)Wbf, bih_f, bhh_f, Ain);
    lstm_bwd_kernel<<<dim3(128), dim3(256), 0, stream>>>(
        (unsigned short*)AfA, (unsigned short*)AfB, hbuf, Ain,
        (const unsigned short*)Bfrag, flags,
        seq, lens, Wih_b, bih_b, bhh_b, hb);
    head_fused_kernel<<<dim3(1), dim3(1024), 0, stream>>>(
        hbuf, hb, lens, Wfc, bfc, gamma, beta, outp);
}

// Round 9
// 408.199 us; speedup vs baseline: 1.0930x; 1.0004x over previous
//
#include <hip/hip_runtime.h>
#include <math.h>

#define BB_ 32   // batch
#define PP_ 24   // sentences
#define SS_ 48   // tokens
#define HH_ 512  // hidden
#define FF_ 64   // feature
#define DD_ 576  // H+F
#define G4_ 2048 // 4H

typedef __attribute__((ext_vector_type(8))) short short8;
typedef __attribute__((ext_vector_type(4))) float f32x4;

__device__ __forceinline__ float sigf(float x) { return 1.f / (1.f + expf(-x)); }

__device__ __forceinline__ unsigned short f2bf(float f) {
    unsigned int u = __float_as_uint(f);
    u += 0x7FFFu + ((u >> 16) & 1u);     // RNE
    return (unsigned short)(u >> 16);
}

// ---------------------------------------------------------------------------
// LAUNCH 1: fused [attn | weight prep | zeroing]. grid 2465 x 256.
//  blk [0,768):     attention+pooling; also writes bf16 copy of seq row
//  blk [768,1280):  Whh_f -> bf16 B-fragment order (64-block fwd tiling)
//  blk [1280,2432): Wih_f -> bf16 row-major
//  blk [2432,2464): zero AfA (h0 fragments)
//  blk 2464:        zero flag BROADCAST MATRIX (4096 lines x 256B = 1MB):
//                   line (c*64+p) is written ONLY by producer p, read ONLY
//                   by consumer c -> single-writer single-reader per line.
// ---------------------------------------------------------------------------
__global__ void __launch_bounds__(256) prep_attn_kernel(
        const int* __restrict__ x, const unsigned int* __restrict__ maskw,
        const float* __restrict__ x_feature, const float* __restrict__ emb,
        const float* __restrict__ w_attn, const float* __restrict__ b_attn,
        const float* __restrict__ Whh, unsigned short* __restrict__ Bf,
        const float* __restrict__ Wih, unsigned short* __restrict__ Wbf,
        float* __restrict__ AfA, int* __restrict__ flags,
        float* __restrict__ seq, unsigned short* __restrict__ seqb)
{
    int blk = blockIdx.x, tid = threadIdx.x;
    if (blk < 768) {
        __shared__ float sc_s[SS_], alpha_s[SS_];
        __shared__ int vtok[SS_], vpos[SS_];
        __shared__ int nv_s, s_u8, s_f32;
        __shared__ int idx_s[SS_];
        __shared__ unsigned char msk_s[SS_];
        if (tid == 0) { s_u8 = 0; s_f32 = 0; }
        __syncthreads();
        int u8 = 0, f32 = 0;
        for (int i = tid; i < 9216; i += 256) {     // mask dtype detect (L2-hot)
            unsigned int w = maskw[i];
            if (w == 0x3F800000u) f32 = 1;
            else if (w > 1u) u8 = 1;
        }
        if (u8) s_u8 = 1;
        if (f32) s_f32 = 1;
        __syncthreads();
        int mode = s_f32 ? 2 : (s_u8 ? 1 : 0);
        int bp = blk, b = bp / PP_, p = bp % PP_;
        if (tid < SS_) {
            size_t i = (size_t)bp * SS_ + tid;
            idx_s[tid] = x[i];
            unsigned char mv;
            if (mode == 1)      mv = ((const unsigned char*)maskw)[i];
            else if (mode == 2) mv = (((const float*)maskw)[i] != 0.f);
            else                mv = (((const int*)maskw)[i] != 0);
            msk_s[tid] = mv;
        }
        __syncthreads();
        if (tid == 0) {                              // compact valid tokens
            int nv = 0;
            for (int s = 0; s < SS_; ++s)
                if (!msk_s[s]) { vtok[nv] = idx_s[s]; vpos[nv] = s; ++nv; }
            nv_s = nv;
        }
        __syncthreads();
        int nv = nv_s;
        int wave = tid >> 6, lane = tid & 63;
        float4 wa0 = ((const float4*)w_attn)[lane];        // regs, no LDS bank hits
        float4 wa1 = ((const float4*)w_attn)[64 + lane];
        for (int j = wave; j < nv; j += 4) {
            const float4* er4 = (const float4*)(emb + (size_t)vtok[j] * HH_);
            float4 v0 = er4[lane], v1 = er4[64 + lane];    // coalesced full row
            float acc = v0.x * wa0.x + v0.y * wa0.y + v0.z * wa0.z + v0.w * wa0.w
                      + v1.x * wa1.x + v1.y * wa1.y + v1.z * wa1.z + v1.w * wa1.w;
            #pragma unroll
            for (int off = 32; off > 0; off >>= 1) acc += __shfl_down(acc, off, 64);
            if (lane == 0) sc_s[j] = acc + b_attn[0];
        }
        __syncthreads();
        if (tid == 0) {                              // softmax over valid subset
            float m = -3.4e38f;
            for (int j = 0; j < nv; ++j) if (sc_s[j] > m) m = sc_s[j];
            float sum = 0.f;
            for (int j = 0; j < nv; ++j) { float a = expf(sc_s[j] - m); alpha_s[j] = a; sum += a; }
            float inv = (nv > 0) ? (1.f / sum) : 0.f;
            for (int j = 0; j < nv; ++j) alpha_s[j] *= inv;
        }
        __syncthreads();
        float acc0 = 0.f, acc1 = 0.f;
        for (int j = 0; j < nv; ++j) {               // branch-free, pipelines
            float a = alpha_s[j];
            const float* er = emb + (size_t)vtok[j] * HH_;
            acc0 += a * er[tid];
            acc1 += a * er[tid + 256];
        }
        float* orow = seq + ((size_t)p * BB_ + b) * DD_;
        unsigned short* ob = seqb + ((size_t)p * BB_ + b) * DD_;
        orow[tid] = acc0;
        orow[tid + 256] = acc1;
        ob[tid] = f2bf(acc0);
        ob[tid + 256] = f2bf(acc1);
        if (tid < FF_) {
            float accF = 0.f;
            for (int j = 0; j < nv; ++j)
                accF += x_feature[((size_t)bp * SS_ + vpos[j]) * FF_ + tid];
            orow[HH_ + tid] = accF;
            ob[HH_ + tid] = f2bf(accF);
        }
    } else if (blk < 1280) {
        int idx = (blk - 768) * 256 + tid;          // Whh -> B-fragment order (64-blk)
        int lane = idx & 63;
        int ks = (idx >> 6) & 15;
        int ti = (idx >> 10) & 1;
        int nb = idx >> 11;
        int c = lane & 15, q = lane >> 4;
        int nrow = (ti * 2 + (c >> 3)) * HH_ + nb * 8 + (c & 7);
        int k0 = ks * 32 + q * 8;
        const float* src = Whh + (size_t)nrow * HH_ + k0;
        unsigned int w0 = (unsigned int)f2bf(src[0]) | ((unsigned int)f2bf(src[1]) << 16);
        unsigned int w1 = (unsigned int)f2bf(src[2]) | ((unsigned int)f2bf(src[3]) << 16);
        unsigned int w2 = (unsigned int)f2bf(src[4]) | ((unsigned int)f2bf(src[5]) << 16);
        unsigned int w3 = (unsigned int)f2bf(src[6]) | ((unsigned int)f2bf(src[7]) << 16);
        *(uint4*)(Bf + (size_t)idx * 8) = make_uint4(w0, w1, w2, w3);
    } else if (blk < 2432) {
        int i = (blk - 1280) * 256 + tid;           // Wih -> bf16 (294912 x4)
        float4 v = ((const float4*)Wih)[i];
        ushort4 o;
        o.x = f2bf(v.x); o.y = f2bf(v.y); o.z = f2bf(v.z); o.w = f2bf(v.w);
        ((ushort4*)Wbf)[i] = o;
    } else if (blk < 2464) {
        int idx = (blk - 2432) * 256 + tid;
        if (idx < 8192) AfA[idx] = 0.f;             // h0 fragments = 0
    } else {
        for (int i = tid; i < 4096; i += 256)       // zero flag matrix
            flags[i * 64] = 0;
    }
}

// ---------------------------------------------------------------------------
// LAUNCH 2: input-gate GEMM via MFMA bf16. A is pre-converted bf16 (seqb) --
// no per-iteration f2bf VALU work.
// ---------------------------------------------------------------------------
__global__ void __launch_bounds__(256) in_gates_mfma_kernel(
        const unsigned short* __restrict__ Ab,
        const unsigned short* __restrict__ Wbf,
        const float* __restrict__ bih,
        const float* __restrict__ bhh,
        float* __restrict__ Cout)
{
    int tid = threadIdx.x, lane = tid & 63, w = tid >> 6;
    int m0 = blockIdx.y * 16;
    int nb = blockIdx.x * 128 + w * 32;
    int c = lane & 15, q = lane >> 4;
    const unsigned short* Ap  = Ab  + (size_t)(m0 + c) * DD_ + q * 8;
    const unsigned short* Bp0 = Wbf + (size_t)(nb + c) * DD_ + q * 8;
    const unsigned short* Bp1 = Bp0 + 16 * DD_;
    f32x4 acc0 = {0.f, 0.f, 0.f, 0.f}, acc1 = {0.f, 0.f, 0.f, 0.f};
    for (int k = 0; k < DD_; k += 32) {
        short8 a  = *(const short8*)(Ap  + k);
        short8 b0 = *(const short8*)(Bp0 + k);
        short8 b1 = *(const short8*)(Bp1 + k);
        acc0 = __builtin_amdgcn_mfma_f32_16x16x32_bf16(a, b0, acc0, 0, 0, 0);
        acc1 = __builtin_amdgcn_mfma_f32_16x16x32_bf16(a, b1, acc1, 0, 0, 0);
    }
    #pragma unroll
    for (int r = 0; r < 4; ++r) {
        int m = m0 + q * 4 + r;
        int n0 = nb + c, n1 = nb + 16 + c;
        Cout[(size_t)m * G4_ + n0] = acc0[r] + bih[n0] + bhh[n0];
        Cout[(size_t)m * G4_ + n1] = acc1[r] + bih[n1] + bhh[n1];
    }
}

// ---------------------------------------------------------------------------
// LAUNCH 3: fused [persistent fwd LSTM | backward one-step]. grid 128 x 256.
//  blk [0,64):   persistent LSTM -- R8 protocol (padded flags, measured 94.6)
//                upgraded to a flag BROADCAST MATRIX: producer p's wave0
//                lanes store t+1 to 64 private lines flagmat[(c*64+p)*64]
//                (one per consumer, issued after the same drain barrier);
//                consumer c's wave0 lane p polls flagmat[(c*64+p)*64].
//                Every flag line: ONE writer, ONE reader -> read fan-in 64x
//                lower than R8.
//  blk [64,128): backward-LSTM collapsed single step.
// All 128 blocks co-resident (<=2 blocks/CU at 76 KB LDS) -> no deadlock.
// ---------------------------------------------------------------------------
__global__ void __launch_bounds__(256) lstm_bwd_kernel(
        unsigned short* __restrict__ AfA, unsigned short* __restrict__ AfB,
        float* __restrict__ hbuf, const float* __restrict__ Ain,
        const unsigned short* __restrict__ Bfrag, int* __restrict__ flags,
        const float* __restrict__ seq, const int* __restrict__ lens,
        const float* __restrict__ Wih_b, const float* __restrict__ bih_b,
        const float* __restrict__ bhh_b, float* __restrict__ hbw)
{
    __shared__ float smem[19040];   // union: lstm {gl 1056f + hstage} | bwd {xsT 19008f + pl}
    int tid = threadIdx.x;
    if (blockIdx.x < 64) {
        float* gl = smem;
        unsigned short* hstage = (unsigned short*)(smem + 1056);
        int lane = tid & 63, wv = tid >> 6;
        int mt = wv & 1, ti = wv >> 1;
        int nb = blockIdx.x;
        const short8* Bp = (const short8*)Bfrag + (((size_t)nb * 2 + ti) * 16) * 64 + lane;
        short8 bfr[16];
        #pragma unroll
        for (int ks = 0; ks < 16; ++ks) bfr[ks] = Bp[ks * 64];
        int c = lane & 15, q = lane >> 4;
        int g = ti * 2 + (c >> 3), ul = c & 7;
        int b2 = tid >> 3, u2 = tid & 7;
        int ug = nb * 8 + u2;
        float creg = 0.f;
        for (int t = 0; t < PP_; ++t) {
            const unsigned short* Af = (t & 1) ? AfB : AfA;
            unsigned short* An       = (t & 1) ? AfA : AfB;
            const float* Ain_t = Ain + (size_t)t * BB_ * G4_;
            float ainv[4];
            #pragma unroll
            for (int r = 0; r < 4; ++r)
                ainv[r] = Ain_t[(size_t)(mt * 16 + q * 4 + r) * G4_ + g * HH_ + nb * 8 + ul];
            const unsigned long long* Ap64 =
                (const unsigned long long*)Af + ((size_t)(mt * 16) * 64 + lane) * 2;
            short8 a[16];
            #pragma unroll
            for (int ks = 0; ks < 16; ++ks) {
                unsigned long long lo = __hip_atomic_load(Ap64 + (size_t)ks * 128,
                        __ATOMIC_RELAXED, __HIP_MEMORY_SCOPE_AGENT);
                unsigned long long hi = __hip_atomic_load(Ap64 + (size_t)ks * 128 + 1,
                        __ATOMIC_RELAXED, __HIP_MEMORY_SCOPE_AGENT);
                union { unsigned long long u[2]; short8 s; } cv;
                cv.u[0] = lo; cv.u[1] = hi;
                a[ks] = cv.s;
            }
            // two independent accumulator chains -> half the serial MFMA latency
            f32x4 acA = {0.f, 0.f, 0.f, 0.f}, acB = {0.f, 0.f, 0.f, 0.f};
            #pragma unroll
            for (int ks = 0; ks < 16; ks += 2) {
                acA = __builtin_amdgcn_mfma_f32_16x16x32_bf16(a[ks],     bfr[ks],     acA, 0, 0, 0);
                acB = __builtin_amdgcn_mfma_f32_16x16x32_bf16(a[ks + 1], bfr[ks + 1], acB, 0, 0, 0);
            }
            #pragma unroll
            for (int r = 0; r < 4; ++r) {
                float v = acA[r] + acB[r] + ainv[r];
                v = (g == 2) ? tanhf(v) : sigf(v);
                gl[(g * 8 + ul) * 33 + (mt * 16 + q * 4 + r)] = v;
            }
            __syncthreads();
            float iv = gl[(0  + u2) * 33 + b2];
            float fv = gl[(8  + u2) * 33 + b2];
            float gv = gl[(16 + u2) * 33 + b2];
            float ov = gl[(24 + u2) * 33 + b2];
            creg = fv * creg + iv * gv;
            float h = ov * tanhf(creg);
            if (t == PP_ - 1) {
                hbuf[(size_t)b2 * HH_ + ug] = h;
            } else {
                hstage[tid] = f2bf(h);
                __syncthreads();
                if (tid < 64) {
                    int b2s = tid >> 1, hf2 = tid & 1;
                    const unsigned short* hp = &hstage[b2s * 8 + hf2 * 4];
                    unsigned long long v = (unsigned long long)hp[0]
                                         | ((unsigned long long)hp[1] << 16)
                                         | ((unsigned long long)hp[2] << 32)
                                         | ((unsigned long long)hp[3] << 48);
                    size_t ub = ((((size_t)(b2s >> 4)) * 16 + (nb >> 2)) * 64
                                 + ((b2s & 15) + 16 * (nb & 3))) * 8 + hf2 * 4;
                    __hip_atomic_store((unsigned long long*)(An + ub), v,
                                       __ATOMIC_RELAXED, __HIP_MEMORY_SCOPE_AGENT);
                }
                __syncthreads();   // vmcnt(0): h stores at coherence point
                if (tid < 64)      // broadcast: one private line per consumer
                    __hip_atomic_store(&flags[((size_t)tid * 64 + nb) * 64], t + 1,
                                       __ATOMIC_RELAXED, __HIP_MEMORY_SCOPE_AGENT);
                if (tid < 64) {    // poll own private lines (sole reader)
                    int target = t + 1;
                    while (true) {
                        int v = __hip_atomic_load(&flags[((size_t)nb * 64 + tid) * 64],
                                __ATOMIC_RELAXED, __HIP_MEMORY_SCOPE_AGENT);
                        if (__all(v >= target)) break;
                        __builtin_amdgcn_s_sleep(1);
                    }
                }
                __syncthreads();
            }
        }
    } else {
        float* xsT = smem;
        int* pl = (int*)(smem + 19008);
        int blk2 = blockIdx.x - 64;
        if (tid < BB_) pl[tid] = lens[tid] - 1;
        __syncthreads();
        for (int idx = tid; idx < BB_ * DD_; idx += 256) {
            int b2 = idx / DD_;
            int k = idx - b2 * DD_;
            xsT[k * 33 + b2] = seq[((size_t)pl[b2] * BB_ + b2) * DD_ + k];
        }
        __syncthreads();
        int b = tid & 31, ul = tid >> 5;
        int u = blk2 * 8 + ul;
        const float* wi = Wih_b + (size_t)u * DD_;
        const float* wg = Wih_b + (size_t)(2 * HH_ + u) * DD_;
        const float* wo = Wih_b + (size_t)(3 * HH_ + u) * DD_;
        float gi = 0.f, gg = 0.f, go = 0.f;
        #pragma unroll 4
        for (int k = 0; k < DD_; k += 4) {
            float4 w1 = *(const float4*)(wi + k);
            float4 w2 = *(const float4*)(wg + k);
            float4 w3 = *(const float4*)(wo + k);
            float x0 = xsT[(k + 0) * 33 + b];
            float x1 = xsT[(k + 1) * 33 + b];
            float x2 = xsT[(k + 2) * 33 + b];
            float x3 = xsT[(k + 3) * 33 + b];
            gi += w1.x * x0 + w1.y * x1 + w1.z * x2 + w1.w * x3;
            gg += w2.x * x0 + w2.y * x1 + w2.z * x2 + w2.w * x3;
            go += w3.x * x0 + w3.y * x1 + w3.z * x2 + w3.w * x3;
        }
        gi += bih_b[u] + bhh_b[u];
        gg += bih_b[2 * HH_ + u] + bhh_b[2 * HH_ + u];
        go += bih_b[3 * HH_ + u] + bhh_b[3 * HH_ + u];
        float cc = sigf(gi) * tanhf(gg);   // c0 = 0
        hbw[(size_t)b * HH_ + u] = sigf(go) * tanhf(cc);
    }
}

// ---------------------------------------------------------------------------
// LAUNCH 4: fused head, one block x 1024 thr (unchanged).
// ---------------------------------------------------------------------------
__global__ void __launch_bounds__(1024) head_fused_kernel(
        const float* __restrict__ hf, const float* __restrict__ hbwd,
        const int* __restrict__ lens,
        const float* __restrict__ Wfc, const float* __restrict__ bfc,
        const float* __restrict__ gamma, const float* __restrict__ beta,
        float* __restrict__ out)
{
    __shared__ float tileL[32 * 1024];   // 128 KB
    __shared__ float lmask[BB_];
    __shared__ float part[1024];
    __shared__ float ys[16][33];
    __shared__ float cstat[16];
    int tid = threadIdx.x;
    if (tid < BB_) lmask[tid] = (lens[tid] == PP_) ? 1.f : 0.f;
    __syncthreads();
    for (int j = tid; j < 32 * 1024; j += 1024) {
        int bb = j >> 10, col = j & 1023;
        float v = (col < HH_) ? hf[(size_t)bb * HH_ + col]
                              : hbwd[(size_t)bb * HH_ + col - HH_];
        tileL[j] = v * lmask[bb];
    }
    __syncthreads();
    int outi = tid & 511, half = tid >> 9;
    int i = outi >> 4, o = outi & 15;
    const float* wrow = Wfc + (size_t)o * 1024;
    float acc = 0.f;
    for (int q = 0; q < 32; ++q) {
        int j = i * 32 + q;
        #pragma unroll
        for (int bb2 = 0; bb2 < 16; ++bb2) {
            int bb = half * 16 + bb2;
            acc += tileL[bb * 1024 + j] * wrow[q * 32 + bb];
        }
    }
    part[tid] = acc;
    __syncthreads();
    if (tid < 512) ys[o][i] = part[tid] + part[tid + 512] + bfc[o];
    __syncthreads();
    if (tid < 16) {
        float mean = 0.f;
        for (int ii = 0; ii < 32; ++ii) mean += ys[tid][ii];
        mean *= (1.f / 32.f);
        float var = 0.f;
        for (int ii = 0; ii < 32; ++ii) { float d = ys[tid][ii] - mean; var += d * d; }
        var *= (1.f / 32.f);
        float inv = 1.f / sqrtf(var + 1e-5f);
        float gmm = gamma[tid], bt = beta[tid];
        float mx = -3.4e38f;
        for (int ii = 0; ii < 32; ++ii) {
            float v = gmm * (ys[tid][ii] - mean) * inv + bt;
            v = fmaxf(v, 0.f);
            ys[tid][ii] = v;
            mx = fmaxf(mx, v);
        }
        float s = 0.f;
        for (int ii = 0; ii < 32; ++ii) s += expf(ys[tid][ii] - mx);
        cstat[tid] = mx + logf(s);
    }
    __syncthreads();
    if (tid < 512) out[tid] = ys[o][i] - cstat[o];
}

extern "C" void kernel_launch(void* const* d_in, const int* in_sizes, int n_in,
                              void* d_out, int out_size, void* d_ws, size_t ws_size,
                              hipStream_t stream) {
    const int* x            = (const int*)d_in[0];
    const void* xm          = d_in[1];
    const float* x_feature  = (const float*)d_in[2];
    const int* lens         = (const int*)d_in[3];
    const float* emb    = (const float*)d_in[6];
    const float* w_attn = (const float*)d_in[7];
    const float* b_attn = (const float*)d_in[8];
    const float* Wih_f  = (const float*)d_in[9];
    const float* Whh_f  = (const float*)d_in[10];
    const float* bih_f  = (const float*)d_in[11];
    const float* bhh_f  = (const float*)d_in[12];
    const float* Wih_b  = (const float*)d_in[13];
    const float* bih_b  = (const float*)d_in[15];
    const float* bhh_b  = (const float*)d_in[16];
    const float* Wfc    = (const float*)d_in[17];
    const float* bfc    = (const float*)d_in[18];
    const float* gamma  = (const float*)d_in[19];
    const float* beta   = (const float*)d_in[20];

    float* ws    = (float*)d_ws;
    float* seq   = ws;                                    // 442368 f
    float* Ain   = seq + (size_t)PP_ * BB_ * DD_;         // 1572864 f
    float* hb    = Ain + (size_t)PP_ * BB_ * G4_;         // 16384 f
    float* hbuf  = hb + (size_t)BB_ * HH_;                // 16384 f
    float* AfA   = hbuf + (size_t)BB_ * HH_;              // 8192 f (16384 bf16)
    float* AfB   = AfA + 8192;                            // 8192 f
    float* Bfrag = AfB + 8192;                            // 524288 f (1M bf16)
    float* Wbf   = Bfrag + 524288;                        // 589824 f (1.18M bf16)
    int*  flags  = (int*)(Wbf + 589824);                  // 4096 lines x 64 ints (1MB)
    unsigned short* seqb = (unsigned short*)(Wbf + 589824 + 262144); // 442368 bf16

    float* outp = (float*)d_out;

    prep_attn_kernel<<<dim3(2465), dim3(256), 0, stream>>>(
        x, (const unsigned int*)xm, x_feature, emb, w_attn, b_attn,
        Whh_f, (unsigned short*)Bfrag, Wih_f, (unsigned short*)Wbf,
        AfA, flags, seq, seqb);
    in_gates_mfma_kernel<<<dim3(16, 48), dim3(256), 0, stream>>>(
        seqb, (const unsigned short*)Wbf, bih_f, bhh_f, Ain);
    lstm_bwd_kernel<<<dim3(128), dim3(256), 0, stream>>>(
        (unsigned short*)AfA, (unsigned short*)AfB, hbuf, Ain,
        (const unsigned short*)Bfrag, flags,
        seq, lens, Wih_b, bih_b, bhh_b, hb);
    head_fused_kernel<<<dim3(1), dim3(1024), 0, stream>>>(
        hbuf, hb, lens, Wfc, bfc, gamma, beta, outp);
}